// Round 1
// baseline (87.933 us; speedup 1.0000x reference)
//
#include <hip/hip_runtime.h>

#define SIGMA_INV 1.0e4f
#define GAMMA_INV 1.0e4f
#define ZNEARC 0.1f
#define ZFARC 50.0f
#define EPSV 1e-10f

__global__ __launch_bounds__(256) void softblend_kernel(
    const float* __restrict__ texels,
    const float* __restrict__ dists,
    const float* __restrict__ zbuf,
    const int*   __restrict__ pix,
    float* __restrict__ out,
    int npix)
{
    const float zscale = 1.0f / (ZFARC - ZNEARC);
    const int stride = gridDim.x * blockDim.x;
    for (int i = blockIdx.x * blockDim.x + threadIdx.x; i < npix; i += stride) {
        const float4* dp = reinterpret_cast<const float4*>(dists + (size_t)i * 8);
        float4 dv0 = dp[0], dv1 = dp[1];
        const float4* zp = reinterpret_cast<const float4*>(zbuf + (size_t)i * 8);
        float4 zv0 = zp[0], zv1 = zp[1];
        const int4* pp = reinterpret_cast<const int4*>(pix + (size_t)i * 8);
        int4 pv0 = pp[0], pv1 = pp[1];

        float4 t[6];
        const float4* tp = reinterpret_cast<const float4*>(texels + (size_t)i * 24);
        #pragma unroll
        for (int j = 0; j < 6; ++j) t[j] = tp[j];
        const float* tf = reinterpret_cast<const float*>(t);

        float d[8] = {dv0.x, dv0.y, dv0.z, dv0.w, dv1.x, dv1.y, dv1.z, dv1.w};
        float z[8] = {zv0.x, zv0.y, zv0.z, zv0.w, zv1.x, zv1.y, zv1.z, zv1.w};
        int   p[8] = {pv0.x, pv0.y, pv0.z, pv0.w, pv1.x, pv1.y, pv1.z, pv1.w};

        float prob[8], zinv[8];
        float zmax = EPSV;
        float alpha = 1.0f;
        #pragma unroll
        for (int k = 0; k < 8; ++k) {
            const bool m = p[k] >= 0;
            // sigmoid(-d/sigma) = 1 / (1 + exp(d/sigma))
            const float pr = m ? 1.0f / (1.0f + __expf(d[k] * SIGMA_INV)) : 0.0f;
            prob[k] = pr;
            alpha *= (1.0f - pr);
            const float zi = m ? (ZFARC - z[k]) * zscale : 0.0f;
            zinv[k] = zi;
            zmax = fmaxf(zmax, zi);
        }

        const float delta = fmaxf(__expf((EPSV - zmax) * GAMMA_INV), EPSV);
        float denom = delta;
        float wn[8];
        #pragma unroll
        for (int k = 0; k < 8; ++k) {
            const float w = prob[k] * __expf((zinv[k] - zmax) * GAMMA_INV);
            wn[k] = w;
            denom += w;
        }
        const float inv = 1.0f / denom;

        // BG = (1,1,1): rgb_c = (sum_k wn_k * tex_kc + delta) / denom
        float r = delta, g = delta, b = delta;
        #pragma unroll
        for (int k = 0; k < 8; ++k) {
            r += wn[k] * tf[k * 3 + 0];
            g += wn[k] * tf[k * 3 + 1];
            b += wn[k] * tf[k * 3 + 2];
        }

        float4 o;
        o.x = r * inv;
        o.y = g * inv;
        o.z = b * inv;
        o.w = 1.0f - alpha;
        reinterpret_cast<float4*>(out)[i] = o;
    }
}

extern "C" void kernel_launch(void* const* d_in, const int* in_sizes, int n_in,
                              void* d_out, int out_size, void* d_ws, size_t ws_size,
                              hipStream_t stream) {
    const float* texels = (const float*)d_in[0];
    const float* dists  = (const float*)d_in[1];
    const float* zbuf   = (const float*)d_in[2];
    const int*   pix    = (const int*)d_in[3];
    float* out = (float*)d_out;

    const int npix = in_sizes[1] / 8;  // dists is [N,H,W,K=8]
    const int block = 256;
    int grid = (npix + block - 1) / block;
    if (grid > 2048) grid = 2048;
    softblend_kernel<<<grid, block, 0, stream>>>(texels, dists, zbuf, pix, out, npix);
}

// Round 3
// 78.198 us; speedup vs baseline: 1.1245x; 1.1245x over previous
//
#include <hip/hip_runtime.h>

#define SIGMA_INV 1.0e4f
#define GAMMA_INV 1.0e4f
#define ZNEARC 0.1f
#define ZFARC 50.0f
#define EPSV 1e-10f

typedef float f32x4 __attribute__((ext_vector_type(4)));

__global__ __launch_bounds__(256) void softblend_kernel(
    const float* __restrict__ texels,
    const float* __restrict__ dists,
    const float* __restrict__ zbuf,
    const int*   __restrict__ pix,
    float* __restrict__ out,
    int npix)
{
    const int i = blockIdx.x * blockDim.x + threadIdx.x;
    if (i >= npix) return;

    // Issue ALL global loads up front — 12 x dwordx4 in flight per lane.
    const float4* dp = reinterpret_cast<const float4*>(dists + (size_t)i * 8);
    const float4* zp = reinterpret_cast<const float4*>(zbuf + (size_t)i * 8);
    const int4*   pp = reinterpret_cast<const int4*>(pix + (size_t)i * 8);
    const float4* tp = reinterpret_cast<const float4*>(texels + (size_t)i * 24);

    float4 dv0 = dp[0], dv1 = dp[1];
    float4 zv0 = zp[0], zv1 = zp[1];
    int4   pv0 = pp[0], pv1 = pp[1];
    float4 t0 = tp[0], t1 = tp[1], t2 = tp[2], t3 = tp[3], t4 = tp[4], t5 = tp[5];

    const float zscale = 1.0f / (ZFARC - ZNEARC);

    float d[8] = {dv0.x, dv0.y, dv0.z, dv0.w, dv1.x, dv1.y, dv1.z, dv1.w};
    float z[8] = {zv0.x, zv0.y, zv0.z, zv0.w, zv1.x, zv1.y, zv1.z, zv1.w};
    int   p[8] = {pv0.x, pv0.y, pv0.z, pv0.w, pv1.x, pv1.y, pv1.z, pv1.w};

    float prob[8], zinv[8];
    float zmax = EPSV;
    float alpha = 1.0f;
    #pragma unroll
    for (int k = 0; k < 8; ++k) {
        const bool m = p[k] >= 0;
        const float pr = m ? 1.0f / (1.0f + __expf(d[k] * SIGMA_INV)) : 0.0f;
        prob[k] = pr;
        alpha *= (1.0f - pr);
        const float zi = m ? (ZFARC - z[k]) * zscale : 0.0f;
        zinv[k] = zi;
        zmax = fmaxf(zmax, zi);
    }

    const float delta = fmaxf(__expf((EPSV - zmax) * GAMMA_INV), EPSV);
    float denom = delta;
    float wn[8];
    #pragma unroll
    for (int k = 0; k < 8; ++k) {
        const float w = prob[k] * __expf((zinv[k] - zmax) * GAMMA_INV);
        wn[k] = w;
        denom += w;
    }
    const float inv = 1.0f / denom;

    const float tf[24] = {t0.x, t0.y, t0.z, t0.w, t1.x, t1.y, t1.z, t1.w,
                          t2.x, t2.y, t2.z, t2.w, t3.x, t3.y, t3.z, t3.w,
                          t4.x, t4.y, t4.z, t4.w, t5.x, t5.y, t5.z, t5.w};

    // BG = (1,1,1): rgb_c = (sum_k wn_k * tex_kc + delta) / denom
    float r = delta, g = delta, b = delta;
    #pragma unroll
    for (int k = 0; k < 8; ++k) {
        r += wn[k] * tf[k * 3 + 0];
        g += wn[k] * tf[k * 3 + 1];
        b += wn[k] * tf[k * 3 + 2];
    }

    f32x4 o;
    o.x = r * inv;
    o.y = g * inv;
    o.z = b * inv;
    o.w = 1.0f - alpha;
    __builtin_nontemporal_store(o, reinterpret_cast<f32x4*>(out) + i);
}

extern "C" void kernel_launch(void* const* d_in, const int* in_sizes, int n_in,
                              void* d_out, int out_size, void* d_ws, size_t ws_size,
                              hipStream_t stream) {
    const float* texels = (const float*)d_in[0];
    const float* dists  = (const float*)d_in[1];
    const float* zbuf   = (const float*)d_in[2];
    const int*   pix    = (const int*)d_in[3];
    float* out = (float*)d_out;

    const int npix = in_sizes[1] / 8;  // dists is [N,H,W,K=8]
    const int block = 256;
    const int grid = (npix + block - 1) / block;
    softblend_kernel<<<grid, block, 0, stream>>>(texels, dists, zbuf, pix, out, npix);
}